// Round 8
// baseline (56.874 us; speedup 1.0000x reference)
//
#include <hip/hip_runtime.h>
#include <math.h>

#define NB 4
#define NS 8192
#define ND 2048
#define NK 4096   // int(0.5 * NS)

#define TPB 8                      // tokens per block
#define MV_BLOCKS ((NB * NS) / TPB)   // 4096

typedef float f32x4 __attribute__((ext_vector_type(4)));

// ------------- Kernel 1: matvec + sigmoid (multi-token block) ---------------
// R6 block shape (256 thr, thread t owns columns (j*256+t)*4, j=0,1) but each
// block does 8 consecutive tokens: w slice loaded into 2 float4 regs ONCE,
// 2-deep software pipeline on the h loads, lds[it][4] slot per iteration so
// only one barrier per token. Low VGPR -> full occupancy.
__global__ void __launch_bounds__(256)
router_matvec(const float* __restrict__ hidden,
              const float* __restrict__ w,
              const float* __restrict__ bias,
              float* __restrict__ probs)
{
    const int t = threadIdx.x;
    const int wid = t >> 6, lane = t & 63;
    const int tok0 = blockIdx.x * TPB;

    const int idx0 = t * 4;            // first 1024 floats
    const int idx1 = 1024 + t * 4;     // second 1024 floats

    const f32x4 w0 = *reinterpret_cast<const f32x4*>(w + idx0);
    const f32x4 w1 = *reinterpret_cast<const f32x4*>(w + idx1);
    const float b0 = bias[0];

    __shared__ float lds[TPB][4];

    const float* hp = hidden + (size_t)tok0 * ND;

    // prologue: token 0 loads
    f32x4 a0 = *reinterpret_cast<const f32x4*>(hp + idx0);
    f32x4 a1 = *reinterpret_cast<const f32x4*>(hp + idx1);

#pragma unroll
    for (int it = 0; it < TPB; ++it) {
        f32x4 n0, n1;
        if (it + 1 < TPB) {
            const float* hn = hp + (size_t)(it + 1) * ND;
            n0 = *reinterpret_cast<const f32x4*>(hn + idx0);
            n1 = *reinterpret_cast<const f32x4*>(hn + idx1);
        }

        float acc = a0.x * w0.x + a0.y * w0.y + a0.z * w0.z + a0.w * w0.w
                  + a1.x * w1.x + a1.y * w1.y + a1.z * w1.z + a1.w * w1.w;

#pragma unroll
        for (int off = 32; off; off >>= 1) acc += __shfl_down(acc, off, 64);

        if (lane == 0) lds[it][wid] = acc;
        __syncthreads();
        if (t == 0) {
            const float logit = lds[it][0] + lds[it][1] + lds[it][2] + lds[it][3] + b0;
            probs[tok0 + it] = 1.0f / (1.0f + expf(-logit));
        }

        a0 = n0; a1 = n1;
    }
}

// ---------------- Kernel 2: per-row top-k mask + aux loss (R4 version) -----
// 1024 threads per batch row; 4-pass 8-bit histogram radix select.

__device__ __forceinline__ float block_reduce_float(float v, float* lds)
{
#pragma unroll
    for (int off = 32; off; off >>= 1) v += __shfl_down(v, off, 64);
    const int wid = threadIdx.x >> 6, lane = threadIdx.x & 63;
    __syncthreads();
    if (lane == 0) lds[wid] = v;
    __syncthreads();
    float s = 0.0f;
#pragma unroll
    for (int i = 0; i < 16; ++i) s += lds[i];
    return s;
}

__global__ void __launch_bounds__(1024)
topk_mask(const float* __restrict__ probs,
          float* __restrict__ mask,
          float* __restrict__ aux)
{
    const int b = blockIdx.x;
    const float* row = probs + b * NS;
    float*      mrow = mask  + b * NS;

    const int t = threadIdx.x;
    const int base = t * 8;
    const int wid = t >> 6, lane = t & 63;

    __shared__ int      hist[256];
    __shared__ float    flds[16];
    __shared__ unsigned sbc[2];     // [0]=prefix, [1]=remaining

    float    v[8];
    unsigned u[8];
#pragma unroll
    for (int i = 0; i < 8; ++i) {
        v[i] = row[base + i];
        u[i] = __float_as_uint(v[i]);   // sigmoid > 0 => uint order == float order
    }

    // ---- row sum (deterministic) for aux loss ----
    float s = 0.0f;
#pragma unroll
    for (int i = 0; i < 8; ++i) s += v[i];
    const float rowsum = block_reduce_float(s, flds);

    // ---- 4-pass MSB radix select for the NK-th largest bit pattern ----
    unsigned prefix = 0;      // resolved high bits
    int remaining = NK;       // rank still needed inside the prefix group
#pragma unroll 1
    for (int pass = 0; pass < 4; ++pass) {
        const int shift = 24 - 8 * pass;
        if (t < 256) hist[t] = 0;
        __syncthreads();

        const unsigned pmask = (pass == 0) ? 0u : (0xFFFFFFFFu << (shift + 8));
#pragma unroll
        for (int i = 0; i < 8; ++i)
            if ((u[i] & pmask) == prefix)
                atomicAdd(&hist[(u[i] >> shift) & 0xFF], 1);
        __syncthreads();

        if (wid == 0) {
            // lane owns bins 4*lane .. 4*lane+3
            int cnt[4];
#pragma unroll
            for (int j = 0; j < 4; ++j) cnt[j] = hist[lane * 4 + j];
            const int mysum = cnt[0] + cnt[1] + cnt[2] + cnt[3];

            // reverse inclusive scan: inc = sum over lanes >= lane
            int inc = mysum;
#pragma unroll
            for (int off = 1; off < 64; off <<= 1) {
                const int y = __shfl_down(inc, off, 64);
                if (lane + off < 64) inc += y;
            }
            const int tailT = inc - mysum;   // count strictly above this lane's bins

            // local candidate: max bin d (scan j descending) with T[d] >= remaining
            int best = -1, subT = 0, Tj = tailT;
#pragma unroll
            for (int j = 3; j >= 0; --j) {
                const int Tnew = Tj + cnt[j];          // T[4*lane+j]
                if (best < 0 && Tnew >= (int)remaining) { best = lane * 4 + j; subT = Tj; }
                Tj = Tnew;
            }

            // wave max-reduce on best, carrying subT (= count strictly above best)
#pragma unroll
            for (int off = 32; off; off >>= 1) {
                const int ob = __shfl_down(best, off, 64);
                const int os = __shfl_down(subT, off, 64);
                if (ob > best) { best = ob; subT = os; }
            }
            if (lane == 0) {
                sbc[0] = prefix | ((unsigned)best << shift);
                sbc[1] = (unsigned)(remaining - subT);
            }
        }
        __syncthreads();
        prefix    = sbc[0];
        remaining = (int)sbc[1];
    }
    const unsigned thr = prefix;     // exact bits of the NK-th largest value
    const int need_ties = remaining; // # elements equal to thr to take (lowest idx first)

    // ---- exclusive scan of per-element "== thr" counts in global index order ----
    int eqc = 0;
#pragma unroll
    for (int i = 0; i < 8; ++i) eqc += (u[i] == thr) ? 1 : 0;

    int inc = eqc;                   // wave-level inclusive scan
#pragma unroll
    for (int off = 1; off < 64; off <<= 1) {
        const int y = __shfl_up(inc, off, 64);
        if (lane >= off) inc += y;
    }
    __syncthreads();
    if (lane == 63) hist[wid] = inc;
    __syncthreads();
    if (t == 0) {
        int run = 0;
#pragma unroll
        for (int wv = 0; wv < 16; ++wv) { const int x = hist[wv]; hist[wv] = run; run += x; }
    }
    __syncthreads();
    int run = (inc - eqc) + hist[wid];

    // ---- write mask ----
#pragma unroll
    for (int i = 0; i < 8; ++i) {
        float m;
        if (u[i] > thr)       m = 1.0f;
        else if (u[i] == thr) { m = (run < need_ties) ? 1.0f : 0.0f; ++run; }
        else                  m = 0.0f;
        mrow[base + i] = m;
    }

    // ---- aux loss ----
    if (t == 0) {
        const float mean = rowsum * (1.0f / (float)NS);
        const float d = mean - 0.5f;
        aux[b] = 0.01f * d * d;
    }
}

extern "C" void kernel_launch(void* const* d_in, const int* in_sizes, int n_in,
                              void* d_out, int out_size, void* d_ws, size_t ws_size,
                              hipStream_t stream)
{
    const float* hidden = (const float*)d_in[0];   // [NB, NS, ND] f32
    const float* w      = (const float*)d_in[1];   // [ND] f32
    const float* bias   = (const float*)d_in[2];   // scalar f32

    float* out   = (float*)d_out;
    float* probs = out;                 // [NB, NS]
    float* mask  = out + NB * NS;       // [NB, NS]
    float* aux   = out + 2 * NB * NS;   // [NB]

    router_matvec<<<MV_BLOCKS, 256, 0, stream>>>(hidden, w, bias, probs);
    topk_mask<<<NB, 1024, 0, stream>>>(probs, mask, aux);
}

// Round 9
// 55.311 us; speedup vs baseline: 1.0283x; 1.0283x over previous
//
#include <hip/hip_runtime.h>
#include <math.h>

#define NB 4
#define NS 8192
#define ND 2048
#define NK 4096   // int(0.5 * NS)

// L3 partition: tokens < CACHED_TOKENS use normal (caching) loads -> stay
// Infinity-Cache-resident across graph replays (192 MB < 256 MiB L3).
// Remaining 64 MB streams via non-temporal loads (no-allocate, no eviction).
#define CACHED_TOKENS 24576

typedef float f32x4 __attribute__((ext_vector_type(4)));

// ---------------- Kernel 1: matvec + sigmoid (block-per-token, R6 shape) ----
// 256 threads per token; each thread 2x float4; low VGPR -> 32 waves/CU.
// Per-block uniform branch picks cached vs NT load path.
__global__ void __launch_bounds__(256)
router_matvec(const float* __restrict__ hidden,
              const float* __restrict__ w,
              const float* __restrict__ bias,
              float* __restrict__ probs)
{
    const int token = blockIdx.x;                  // 0 .. NB*NS-1
    const float* hp = hidden + (size_t)token * ND;
    const int t = threadIdx.x;

    const int idx0 = t * 4;
    const int idx1 = 1024 + t * 4;

    const f32x4 w0 = *reinterpret_cast<const f32x4*>(w + idx0);
    const f32x4 w1 = *reinterpret_cast<const f32x4*>(w + idx1);

    f32x4 h0, h1;
    if (token < CACHED_TOKENS) {
        h0 = *reinterpret_cast<const f32x4*>(hp + idx0);
        h1 = *reinterpret_cast<const f32x4*>(hp + idx1);
    } else {
        h0 = __builtin_nontemporal_load(reinterpret_cast<const f32x4*>(hp + idx0));
        h1 = __builtin_nontemporal_load(reinterpret_cast<const f32x4*>(hp + idx1));
    }

    float acc = h0.x * w0.x + h0.y * w0.y + h0.z * w0.z + h0.w * w0.w
              + h1.x * w1.x + h1.y * w1.y + h1.z * w1.z + h1.w * w1.w;

    // wave (64-lane) reduce
#pragma unroll
    for (int off = 32; off; off >>= 1) acc += __shfl_down(acc, off, 64);

    __shared__ float lds[4];
    const int wid = t >> 6, lane = t & 63;
    if (lane == 0) lds[wid] = acc;
    __syncthreads();
    if (t == 0) {
        const float logit = lds[0] + lds[1] + lds[2] + lds[3] + bias[0];
        probs[token] = 1.0f / (1.0f + expf(-logit));
    }
}

// ---------------- Kernel 2: per-row top-k mask + aux loss (R4 version) -----
// 1024 threads per batch row; 4-pass 8-bit histogram radix select.

__device__ __forceinline__ float block_reduce_float(float v, float* lds)
{
#pragma unroll
    for (int off = 32; off; off >>= 1) v += __shfl_down(v, off, 64);
    const int wid = threadIdx.x >> 6, lane = threadIdx.x & 63;
    __syncthreads();
    if (lane == 0) lds[wid] = v;
    __syncthreads();
    float s = 0.0f;
#pragma unroll
    for (int i = 0; i < 16; ++i) s += lds[i];
    return s;
}

__global__ void __launch_bounds__(1024)
topk_mask(const float* __restrict__ probs,
          float* __restrict__ mask,
          float* __restrict__ aux)
{
    const int b = blockIdx.x;
    const float* row = probs + b * NS;
    float*      mrow = mask  + b * NS;

    const int t = threadIdx.x;
    const int base = t * 8;
    const int wid = t >> 6, lane = t & 63;

    __shared__ int      hist[256];
    __shared__ float    flds[16];
    __shared__ unsigned sbc[2];     // [0]=prefix, [1]=remaining

    float    v[8];
    unsigned u[8];
#pragma unroll
    for (int i = 0; i < 8; ++i) {
        v[i] = row[base + i];
        u[i] = __float_as_uint(v[i]);   // sigmoid > 0 => uint order == float order
    }

    // ---- row sum (deterministic) for aux loss ----
    float s = 0.0f;
#pragma unroll
    for (int i = 0; i < 8; ++i) s += v[i];
    const float rowsum = block_reduce_float(s, flds);

    // ---- 4-pass MSB radix select for the NK-th largest bit pattern ----
    unsigned prefix = 0;      // resolved high bits
    int remaining = NK;       // rank still needed inside the prefix group
#pragma unroll 1
    for (int pass = 0; pass < 4; ++pass) {
        const int shift = 24 - 8 * pass;
        if (t < 256) hist[t] = 0;
        __syncthreads();

        const unsigned pmask = (pass == 0) ? 0u : (0xFFFFFFFFu << (shift + 8));
#pragma unroll
        for (int i = 0; i < 8; ++i)
            if ((u[i] & pmask) == prefix)
                atomicAdd(&hist[(u[i] >> shift) & 0xFF], 1);
        __syncthreads();

        if (wid == 0) {
            // lane owns bins 4*lane .. 4*lane+3
            int cnt[4];
#pragma unroll
            for (int j = 0; j < 4; ++j) cnt[j] = hist[lane * 4 + j];
            const int mysum = cnt[0] + cnt[1] + cnt[2] + cnt[3];

            // reverse inclusive scan: inc = sum over lanes >= lane
            int inc = mysum;
#pragma unroll
            for (int off = 1; off < 64; off <<= 1) {
                const int y = __shfl_down(inc, off, 64);
                if (lane + off < 64) inc += y;
            }
            const int tailT = inc - mysum;   // count strictly above this lane's bins

            // local candidate: max bin d (scan j descending) with T[d] >= remaining
            int best = -1, subT = 0, Tj = tailT;
#pragma unroll
            for (int j = 3; j >= 0; --j) {
                const int Tnew = Tj + cnt[j];          // T[4*lane+j]
                if (best < 0 && Tnew >= (int)remaining) { best = lane * 4 + j; subT = Tj; }
                Tj = Tnew;
            }

            // wave max-reduce on best, carrying subT (= count strictly above best)
#pragma unroll
            for (int off = 32; off; off >>= 1) {
                const int ob = __shfl_down(best, off, 64);
                const int os = __shfl_down(subT, off, 64);
                if (ob > best) { best = ob; subT = os; }
            }
            if (lane == 0) {
                sbc[0] = prefix | ((unsigned)best << shift);
                sbc[1] = (unsigned)(remaining - subT);
            }
        }
        __syncthreads();
        prefix    = sbc[0];
        remaining = (int)sbc[1];
    }
    const unsigned thr = prefix;     // exact bits of the NK-th largest value
    const int need_ties = remaining; // # elements equal to thr to take (lowest idx first)

    // ---- exclusive scan of per-element "== thr" counts in global index order ----
    int eqc = 0;
#pragma unroll
    for (int i = 0; i < 8; ++i) eqc += (u[i] == thr) ? 1 : 0;

    int inc = eqc;                   // wave-level inclusive scan
#pragma unroll
    for (int off = 1; off < 64; off <<= 1) {
        const int y = __shfl_up(inc, off, 64);
        if (lane >= off) inc += y;
    }
    __syncthreads();
    if (lane == 63) hist[wid] = inc;
    __syncthreads();
    if (t == 0) {
        int run = 0;
#pragma unroll
        for (int wv = 0; wv < 16; ++wv) { const int x = hist[wv]; hist[wv] = run; run += x; }
    }
    __syncthreads();
    int run = (inc - eqc) + hist[wid];

    // ---- write mask ----
#pragma unroll
    for (int i = 0; i < 8; ++i) {
        float m;
        if (u[i] > thr)       m = 1.0f;
        else if (u[i] == thr) { m = (run < need_ties) ? 1.0f : 0.0f; ++run; }
        else                  m = 0.0f;
        mrow[base + i] = m;
    }

    // ---- aux loss ----
    if (t == 0) {
        const float mean = rowsum * (1.0f / (float)NS);
        const float d = mean - 0.5f;
        aux[b] = 0.01f * d * d;
    }
}

extern "C" void kernel_launch(void* const* d_in, const int* in_sizes, int n_in,
                              void* d_out, int out_size, void* d_ws, size_t ws_size,
                              hipStream_t stream)
{
    const float* hidden = (const float*)d_in[0];   // [NB, NS, ND] f32
    const float* w      = (const float*)d_in[1];   // [ND] f32
    const float* bias   = (const float*)d_in[2];   // scalar f32

    float* out   = (float*)d_out;
    float* probs = out;                 // [NB, NS]
    float* mask  = out + NB * NS;       // [NB, NS]
    float* aux   = out + 2 * NB * NS;   // [NB]

    router_matvec<<<NB * NS, 256, 0, stream>>>(hidden, w, bias, probs);
    topk_mask<<<NB, 1024, 0, stream>>>(probs, mask, aux);
}